// Round 10
// baseline (202.254 us; speedup 1.0000x reference)
//
#include <hip/hip_runtime.h>
#include <cstdint>
#include <cstddef>

// ---------------------------------------------------------------------------
// GCN 3-layer forward, CSR-gather formulation:
//   out[d] = dinv[d] * ( sum_{s in N(d)} T'[s] + T'[d] ) + b,
//   with T'[r] = bf16( dinv[r] * (X[r] @ W) ).
// CSR build: 2-level bucket counting sort, all fine-grained atomics in LDS.
// Round 9: hipMemsetAsync(bucket_tot) removed — the rocclr fill blit cost
// ~42 us/replay (top dispatch in round 8!). k_s2a now derives bucket totals
// by summing blk_off columns; k_s1 loses its global atomics too.
// ---------------------------------------------------------------------------

#define CH 4096      // edges per S1/S3 block
#define BSHIFT 9     // 512 dsts per bucket
#define BSIZE 512
// assumes n <= 131072 (src fits 17 bits, NB <= 256); n = 100000 here.

typedef short bf16x8 __attribute__((ext_vector_type(8)));
typedef float f32x4 __attribute__((ext_vector_type(4)));

__device__ __forceinline__ int eidx_at(const void* p, long long i, int is64) {
  if (is64) return (int)((const long long*)p)[i];
  return ((const int*)p)[i];
}

__device__ __forceinline__ unsigned short f2bf(float f) {
  unsigned u = __float_as_uint(f);
  unsigned r = (u + 0x7FFFu + ((u >> 16) & 1u)) >> 16;   // RNE
  return (unsigned short)r;
}
__device__ __forceinline__ float bf2f(unsigned short h) {
  return __uint_as_float((unsigned)h << 16);
}

__global__ void k_flag(const void* eidx, int* flag) {
  const unsigned long long* p = (const unsigned long long*)eidx;
  int lane = threadIdx.x & 63;
  int bad = 0;
#pragma unroll
  for (int i = 0; i < 4; ++i) bad |= (p[lane + 64 * i] > 1000000000ULL) ? 1 : 0;
  int any_bad = __any(bad);
  if (lane == 0) *flag = any_bad ? 0 : 1;
}

// S1: per-block histogram over buckets (LDS atomics only; no global atomics)
__global__ __launch_bounds__(256) void k_s1(const void* eidx, const int* flag,
                                            int* __restrict__ blk_off,
                                            int E, int NB) {
  __shared__ int h[256];
  int t = threadIdx.x, blk = blockIdx.x;
  if (t < NB) h[t] = 0;
  __syncthreads();
  int is64 = *flag;
  int lo = blk * CH, hi = min(lo + CH, E);
  for (int i = lo + t; i < hi; i += 256) {
    int d = eidx_at(eidx, (long long)E + i, is64);
    atomicAdd(&h[d >> BSHIFT], 1);
  }
  __syncthreads();
  if (t < NB) blk_off[(size_t)blk * NB + t] = h[t];
}

// S2a: sum blk_off columns -> bucket totals, then exclusive scan (NB <= 256)
__global__ __launch_bounds__(256) void k_s2a(const int* __restrict__ blk_off,
                                             int nblk,
                                             int* __restrict__ bucket_base,
                                             int* __restrict__ rowptr,
                                             int NB, int n, int E) {
  int t = threadIdx.x;
  int v = 0;
  if (t < NB) {
    int i = 0;
    int v0 = 0, v1 = 0, v2 = 0, v3 = 0;
    for (; i + 4 <= nblk; i += 4) {
      v0 += blk_off[(size_t)(i + 0) * NB + t];
      v1 += blk_off[(size_t)(i + 1) * NB + t];
      v2 += blk_off[(size_t)(i + 2) * NB + t];
      v3 += blk_off[(size_t)(i + 3) * NB + t];
    }
    for (; i < nblk; ++i) v0 += blk_off[(size_t)i * NB + t];
    v = (v0 + v1) + (v2 + v3);
  }
  __shared__ int sh[256];
  sh[t] = v;
  __syncthreads();
  for (int off = 1; off < 256; off <<= 1) {
    int x = (t >= off) ? sh[t - off] : 0;
    __syncthreads();
    sh[t] += x;
    __syncthreads();
  }
  if (t < NB) bucket_base[t] = sh[t] - v;
  if (t == 0) { bucket_base[NB] = E; rowptr[n] = E; }
}

// S2b: per bucket, scan its per-block counts -> exclusive write ranges
__global__ __launch_bounds__(256) void k_s2b(int* __restrict__ blk_off,
                                             const int* __restrict__ bucket_base,
                                             int nblk, int NB) {
  int b = blockIdx.x, t = threadIdx.x;
  __shared__ int sh[256];
  __shared__ int carry;
  if (t == 0) carry = bucket_base[b];
  __syncthreads();
  for (int tile = 0; tile < nblk; tile += 256) {
    int i = tile + t;
    int v = (i < nblk) ? blk_off[(size_t)i * NB + b] : 0;
    sh[t] = v;
    __syncthreads();
    for (int off = 1; off < 256; off <<= 1) {
      int x = (t >= off) ? sh[t - off] : 0;
      __syncthreads();
      sh[t] += x;
      __syncthreads();
    }
    int c = carry;
    if (i < nblk) blk_off[(size_t)i * NB + b] = c + sh[t] - v;
    int tot = sh[255];
    __syncthreads();
    if (t == 0) carry = c + tot;
    __syncthreads();
  }
}

// S3: scatter packed edges into this block's disjoint bucket ranges
__global__ __launch_bounds__(256) void k_s3(const void* eidx, const int* flag,
                                            const int* __restrict__ blk_off,
                                            unsigned int* __restrict__ packed,
                                            int E, int NB) {
  __shared__ int cur[256];
  int t = threadIdx.x, blk = blockIdx.x;
  if (t < NB) cur[t] = blk_off[(size_t)blk * NB + t];
  __syncthreads();
  int is64 = *flag;
  int lo = blk * CH, hi = min(lo + CH, E);
  for (int i = lo + t; i < hi; i += 256) {
    int s = eidx_at(eidx, i, is64);
    int d = eidx_at(eidx, (long long)E + i, is64);
    int pos = atomicAdd(&cur[d >> BSHIFT], 1);  // LDS atomic
    packed[pos] = ((unsigned)(d & (BSIZE - 1)) << 17) | (unsigned)s;
  }
}

// S4: one block per bucket. LDS hist over 512 local dsts -> rowptr/dinv
// (coalesced), then scatter csr_src within the bucket's window.
__global__ __launch_bounds__(256) void k_s4(const unsigned int* __restrict__ packed,
                                            const int* __restrict__ bucket_base,
                                            int* __restrict__ rowptr,
                                            float* __restrict__ dinv,
                                            int* __restrict__ csr_src, int n) {
  int b = blockIdx.x, t = threadIdx.x;
  int lo = bucket_base[b], hi = bucket_base[b + 1];
  __shared__ int h[BSIZE];
  __shared__ int ps[256];
  __shared__ int cur[BSIZE];
  h[2 * t] = 0; h[2 * t + 1] = 0;
  __syncthreads();
  for (int i = lo + t; i < hi; i += 256)
    atomicAdd(&h[packed[i] >> 17], 1);
  __syncthreads();
  int a0 = h[2 * t], a1 = h[2 * t + 1];
  ps[t] = a0 + a1;
  __syncthreads();
  for (int off = 1; off < 256; off <<= 1) {
    int x = (t >= off) ? ps[t - off] : 0;
    __syncthreads();
    ps[t] += x;
    __syncthreads();
  }
  int pexcl = ps[t] - (a0 + a1);
  int e0 = lo + pexcl, e1 = lo + pexcl + a0;
  cur[2 * t] = e0;
  cur[2 * t + 1] = e1;
  int node0 = b * BSIZE + 2 * t, node1 = b * BSIZE + 2 * t + 1;
  if (node0 < n) { rowptr[node0] = e0; dinv[node0] = rsqrtf((float)(a0 + 1)); }
  if (node1 < n) { rowptr[node1] = e1; dinv[node1] = rsqrtf((float)(a1 + 1)); }
  __syncthreads();
  for (int i = lo + t; i < hi; i += 256) {
    unsigned p = packed[i];
    int j = p >> 17;
    int s = (int)(p & 0x1FFFFu);
    int pos = atomicAdd(&cur[j], 1);  // LDS atomic
    csr_src[pos] = s;
  }
}

// MFMA matmul: T'[r] = bf16(dinv[r] * (X[r] @ W)), one wave per 16 rows.
// Compensated bf16 split: X=Xh+Xl, W=Wh+Wl; acc = XhWh + XhWl + XlWh.
// Layouts (m89/m97): A/B lane l holds 8 contiguous k at k=(l>>4)*8+i,
// row/col = l&15; D: col=l&15, row=(l>>4)*4+reg.  Requires 16 | n... (n%16
// handled by rowb bound check per 16-row tile; n=100000 is 16-aligned).
template <int COUT>
__global__ __launch_bounds__(256) void k_mm(const float* __restrict__ X,
                                            const float* __restrict__ W,
                                            const float* __restrict__ dinv,
                                            unsigned short* __restrict__ T, int n) {
  const int NT = COUT / 16;
  int lane = threadIdx.x & 63;
  int wid = blockIdx.x * (blockDim.x >> 6) + (threadIdx.x >> 6);
  int rowb = wid * 16;
  if (rowb >= n) return;
  int lr = lane & 15;   // A-row / D-col selector
  int lk = lane >> 4;   // k-group selector

  // ---- W fragments (hi/lo), per-lane strided scalar loads (L1/L2-hot) ----
  bf16x8 wh[2 * NT], wl[2 * NT];
#pragma unroll
  for (int kk = 0; kk < 2; ++kk) {
#pragma unroll
    for (int nt = 0; nt < NT; ++nt) {
#pragma unroll
      for (int i = 0; i < 8; ++i) {
        int k = kk * 32 + lk * 8 + i;
        float w = W[k * COUT + nt * 16 + lr];
        unsigned short h = f2bf(w);
        wh[kk * NT + nt][i] = (short)h;
        wl[kk * NT + nt][i] = (short)f2bf(w - bf2f(h));
      }
    }
  }

  // ---- A fragments (hi/lo) from fp32 row, vectorized loads ----
  const float* ar = X + (size_t)(rowb + lr) * 64;
  bf16x8 ah[2], al[2];
#pragma unroll
  for (int kk = 0; kk < 2; ++kk) {
    float4 v0 = *(const float4*)(ar + kk * 32 + lk * 8);
    float4 v1 = *(const float4*)(ar + kk * 32 + lk * 8 + 4);
    float vv[8] = {v0.x, v0.y, v0.z, v0.w, v1.x, v1.y, v1.z, v1.w};
#pragma unroll
    for (int i = 0; i < 8; ++i) {
      unsigned short h = f2bf(vv[i]);
      ah[kk][i] = (short)h;
      al[kk][i] = (short)f2bf(vv[i] - bf2f(h));
    }
  }

  // ---- MFMA: 6 per n-tile (2 k-steps x 3 split terms) ----
  f32x4 acc[NT];
#pragma unroll
  for (int nt = 0; nt < NT; ++nt) {
    f32x4 a = {0.f, 0.f, 0.f, 0.f};
#pragma unroll
    for (int kk = 0; kk < 2; ++kk) {
      a = __builtin_amdgcn_mfma_f32_16x16x32_bf16(ah[kk], wh[kk * NT + nt], a, 0, 0, 0);
      a = __builtin_amdgcn_mfma_f32_16x16x32_bf16(ah[kk], wl[kk * NT + nt], a, 0, 0, 0);
      a = __builtin_amdgcn_mfma_f32_16x16x32_bf16(al[kk], wh[kk * NT + nt], a, 0, 0, 0);
    }
    acc[nt] = a;
  }

  // ---- epilogue: D[m=lk*4+j][n=nt*16+lr] -> dinv scale -> bf16 store ----
#pragma unroll
  for (int j = 0; j < 4; ++j) {
    int row = rowb + lk * 4 + j;
    float dr = dinv[row];
#pragma unroll
    for (int nt = 0; nt < NT; ++nt)
      T[(size_t)row * COUT + nt * 16 + lr] = f2bf(acc[nt][j] * dr);
  }
}

// One wave per dst row: acc = sum T'[src[j]] (batched 8/4/1, independent
// bf16 loads, fp32 accumulate), then out = dinv*(acc + T'[row]) + b.
template <int COUT, bool RELU>
__global__ __launch_bounds__(256) void k_gather(const unsigned short* __restrict__ T,
                                                const int* __restrict__ rowptr,
                                                const int* __restrict__ csr_src,
                                                const float* __restrict__ dinv,
                                                const float* __restrict__ b,
                                                float* __restrict__ out, int n) {
  int wave = blockIdx.x * (blockDim.x >> 6) + (threadIdx.x >> 6);
  int lane = threadIdx.x & 63;
  int row = __builtin_amdgcn_readfirstlane(wave);
  if (row >= n) return;
  int beg = rowptr[row];
  int end = rowptr[row + 1];
  float dr = dinv[row];
  float a0 = 0.f, a1 = 0.f, a2 = 0.f, a3 = 0.f;
  int j = beg;
  if (lane < COUT) {
    for (; j + 8 <= end; j += 8) {
      int s0 = csr_src[j + 0], s1 = csr_src[j + 1], s2 = csr_src[j + 2], s3 = csr_src[j + 3];
      int s4 = csr_src[j + 4], s5 = csr_src[j + 5], s6 = csr_src[j + 6], s7 = csr_src[j + 7];
      float t0 = bf2f(T[(size_t)s0 * COUT + lane]);
      float t1 = bf2f(T[(size_t)s1 * COUT + lane]);
      float t2 = bf2f(T[(size_t)s2 * COUT + lane]);
      float t3 = bf2f(T[(size_t)s3 * COUT + lane]);
      float t4 = bf2f(T[(size_t)s4 * COUT + lane]);
      float t5 = bf2f(T[(size_t)s5 * COUT + lane]);
      float t6 = bf2f(T[(size_t)s6 * COUT + lane]);
      float t7 = bf2f(T[(size_t)s7 * COUT + lane]);
      a0 += t0; a1 += t1; a2 += t2; a3 += t3;
      a0 += t4; a1 += t5; a2 += t6; a3 += t7;
    }
    if (j + 4 <= end) {
      int s0 = csr_src[j + 0], s1 = csr_src[j + 1], s2 = csr_src[j + 2], s3 = csr_src[j + 3];
      float t0 = bf2f(T[(size_t)s0 * COUT + lane]);
      float t1 = bf2f(T[(size_t)s1 * COUT + lane]);
      float t2 = bf2f(T[(size_t)s2 * COUT + lane]);
      float t3 = bf2f(T[(size_t)s3 * COUT + lane]);
      a0 += t0; a1 += t1; a2 += t2; a3 += t3;
      j += 4;
    }
    for (; j < end; ++j) {
      int s = csr_src[j];
      a0 += bf2f(T[(size_t)s * COUT + lane]);
    }
    float acc = (a0 + a1) + (a2 + a3);
    float v = fmaf(dr, acc + bf2f(T[(size_t)row * COUT + lane]), b[lane]);
    if (RELU) v = fmaxf(v, 0.f);
    out[(size_t)row * COUT + lane] = v;
  }
}

extern "C" void kernel_launch(void* const* d_in, const int* in_sizes, int n_in,
                              void* d_out, int out_size, void* d_ws, size_t ws_size,
                              hipStream_t stream) {
  const float* x  = (const float*)d_in[0];
  const void*  ei = d_in[1];
  const float* W1 = (const float*)d_in[2];
  const float* b1 = (const float*)d_in[3];
  const float* W2 = (const float*)d_in[4];
  const float* b2 = (const float*)d_in[5];
  const float* W3 = (const float*)d_in[6];
  const float* b3 = (const float*)d_in[7];
  float* out = (float*)d_out;

  const int n = in_sizes[0] / 64;   // 100000 (multiple of 16)
  const int E = in_sizes[1] / 2;    // 1000000

  const int NB   = (n + BSIZE - 1) / BSIZE;  // 196 buckets
  const int NBLK = (E + CH - 1) / CH;        // 245 edge blocks

  char* ws = (char*)d_ws;
  size_t off = 0;
  auto carve = [&](size_t bytes) -> void* {
    void* p = ws + off;
    off = (off + bytes + 255) & ~(size_t)255;
    return p;
  };
  int*            flag        = (int*)carve(16);
  float*          dinv        = (float*)carve(sizeof(float) * n);
  int*            rowptr      = (int*)carve(sizeof(int) * (n + 1));
  int*            bucket_base = (int*)carve(sizeof(int) * 257);
  int*            blk_off     = (int*)carve(sizeof(int) * (size_t)NBLK * NB);
  unsigned*       packed      = (unsigned*)carve(sizeof(unsigned) * E);
  int*            csr_src     = (int*)carve(sizeof(int) * E);
  unsigned short* T           = (unsigned short*)carve(sizeof(unsigned short) * (size_t)n * 64);
  float*          A           = (float*)carve(sizeof(float) * (size_t)n * 64);

  const int B = 256;
  const int gW  = (n + 3) / 4;                    // gather: 4 waves/block
  const int gMM = ((n + 15) / 16 + 3) / 4;        // mfma: 4 waves/block, 16 rows/wave

  // ---- CSR build (bucket counting sort; no memset, no global atomics) ----
  k_flag<<<1, 64, 0, stream>>>(ei, flag);
  k_s1<<<NBLK, B, 0, stream>>>(ei, flag, blk_off, E, NB);
  k_s2a<<<1, B, 0, stream>>>(blk_off, NBLK, bucket_base, rowptr, NB, n, E);
  k_s2b<<<NB, B, 0, stream>>>(blk_off, bucket_base, NBLK, NB);
  k_s3<<<NBLK, B, 0, stream>>>(ei, flag, blk_off, packed, E, NB);
  k_s4<<<NB, B, 0, stream>>>(packed, bucket_base, rowptr, dinv, csr_src, n);

  // ---- layer 1: x -> A ----
  k_mm<64><<<gMM, B, 0, stream>>>(x, W1, dinv, T, n);
  k_gather<64, true><<<gW, B, 0, stream>>>(T, rowptr, csr_src, dinv, b1, A, n);

  // ---- layer 2: A -> A ----
  k_mm<64><<<gMM, B, 0, stream>>>(A, W2, dinv, T, n);
  k_gather<64, true><<<gW, B, 0, stream>>>(T, rowptr, csr_src, dinv, b2, A, n);

  // ---- layer 3: A -> out ----
  k_mm<32><<<gMM, B, 0, stream>>>(A, W3, dinv, T, n);
  k_gather<32, false><<<gW, B, 0, stream>>>(T, rowptr, csr_src, dinv, b3, out, n);
}

// Round 11
// 185.465 us; speedup vs baseline: 1.0905x; 1.0905x over previous
//
#include <hip/hip_runtime.h>
#include <cstdint>
#include <cstddef>

// ---------------------------------------------------------------------------
// GCN 3-layer forward, CSR-gather formulation:
//   out[d] = dinv[d] * ( sum_{s in N(d)} T'[s] + T'[d] ) + b,
//   with T'[r] = bf16( dinv[r] * (X[r] @ W) ).
// Round 10: (a) activations A stored bf16 -> layer-2/3 MFMA reads bf16
// fragments directly (2-term split: A*Wh + A*Wl), A traffic halved;
// (b) BSIZE 512->256 (s4 was 196 blocks = occupancy-starved);
// (c) k_flag fused into s1/s3. Round-9/10 lesson: top-5 "fill" dispatches
// are HARNESS d_ws poisons outside the timed path — ignore them.
// ---------------------------------------------------------------------------

#define CH 4096      // edges per S1/S3 block (NBLK = 245 <= 256 for colsum)
#define BSHIFT 8     // 256 dsts per bucket
#define BSIZE 256
// assumes n <= 131072 (src fits 17 bits) and NB <= 512; n = 100000 -> NB=391.

typedef short bf16x8 __attribute__((ext_vector_type(8)));
typedef float f32x4 __attribute__((ext_vector_type(4)));

__device__ __forceinline__ int eidx_at(const void* p, long long i, int is64) {
  if (is64) return (int)((const long long*)p)[i];
  return ((const int*)p)[i];
}

// int64 node indices are all < 1e5; int32 data read as u64 has a random index
// in the high word -> huge values. Call from wave 0 only.
__device__ __forceinline__ int detect64(const void* eidx) {
  const unsigned long long* p = (const unsigned long long*)eidx;
  int lane = threadIdx.x & 63;
  int bad = 0;
#pragma unroll
  for (int i = 0; i < 4; ++i) bad |= (p[lane + 64 * i] > 1000000000ULL) ? 1 : 0;
  return __any(bad) ? 0 : 1;
}

__device__ __forceinline__ unsigned short f2bf(float f) {
  unsigned u = __float_as_uint(f);
  unsigned r = (u + 0x7FFFu + ((u >> 16) & 1u)) >> 16;   // RNE
  return (unsigned short)r;
}
__device__ __forceinline__ float bf2f(unsigned short h) {
  return __uint_as_float((unsigned)h << 16);
}

// S1: per-block histogram over buckets (LDS atomics only)
__global__ __launch_bounds__(256) void k_s1(const void* eidx,
                                            int* __restrict__ blk_off,
                                            int E, int NB) {
  __shared__ int h[512];
  __shared__ int s_is64;
  int t = threadIdx.x, blk = blockIdx.x;
  for (int i = t; i < NB; i += 256) h[i] = 0;
  if (t < 64) { int r = detect64(eidx); if (t == 0) s_is64 = r; }
  __syncthreads();
  int is64 = s_is64;
  int lo = blk * CH, hi = min(lo + CH, E);
  for (int i = lo + t; i < hi; i += 256) {
    int d = eidx_at(eidx, (long long)E + i, is64);
    atomicAdd(&h[d >> BSHIFT], 1);
  }
  __syncthreads();
  for (int i = t; i < NB; i += 256) blk_off[(size_t)blk * NB + i] = h[i];
}

// S2a-1: bucket_tot[b] = sum_i blk_off[i][b]   (one block per bucket)
__global__ __launch_bounds__(256) void k_colsum(const int* __restrict__ blk_off,
                                                int nblk, int NB,
                                                int* __restrict__ bucket_tot) {
  int b = blockIdx.x, t = threadIdx.x;
  int v = (t < nblk) ? blk_off[(size_t)t * NB + b] : 0;   // nblk <= 256
  __shared__ int sh[256];
  sh[t] = v;
  __syncthreads();
  for (int off = 128; off > 0; off >>= 1) {
    if (t < off) sh[t] += sh[t + off];
    __syncthreads();
  }
  if (t == 0) bucket_tot[b] = sh[0];
}

// S2a-2: exclusive scan of bucket totals (NB <= 512), one block
__global__ __launch_bounds__(512) void k_scan(const int* __restrict__ bucket_tot,
                                              int* __restrict__ bucket_base,
                                              int* __restrict__ rowptr,
                                              int NB, int n, int E) {
  int t = threadIdx.x;
  __shared__ int sh[512];
  int v = (t < NB) ? bucket_tot[t] : 0;
  sh[t] = v;
  __syncthreads();
  for (int off = 1; off < 512; off <<= 1) {
    int x = (t >= off) ? sh[t - off] : 0;
    __syncthreads();
    sh[t] += x;
    __syncthreads();
  }
  if (t < NB) bucket_base[t] = sh[t] - v;
  if (t == 0) { bucket_base[NB] = E; rowptr[n] = E; }
}

// S2b: per bucket, scan its per-block counts -> exclusive write ranges
__global__ __launch_bounds__(256) void k_s2b(int* __restrict__ blk_off,
                                             const int* __restrict__ bucket_base,
                                             int nblk, int NB) {
  int b = blockIdx.x, t = threadIdx.x;
  __shared__ int sh[256];
  __shared__ int carry;
  if (t == 0) carry = bucket_base[b];
  __syncthreads();
  for (int tile = 0; tile < nblk; tile += 256) {
    int i = tile + t;
    int v = (i < nblk) ? blk_off[(size_t)i * NB + b] : 0;
    sh[t] = v;
    __syncthreads();
    for (int off = 1; off < 256; off <<= 1) {
      int x = (t >= off) ? sh[t - off] : 0;
      __syncthreads();
      sh[t] += x;
      __syncthreads();
    }
    int c = carry;
    if (i < nblk) blk_off[(size_t)i * NB + b] = c + sh[t] - v;
    int tot = sh[255];
    __syncthreads();
    if (t == 0) carry = c + tot;
    __syncthreads();
  }
}

// S3: scatter packed edges into this block's disjoint bucket ranges
__global__ __launch_bounds__(256) void k_s3(const void* eidx,
                                            const int* __restrict__ blk_off,
                                            unsigned int* __restrict__ packed,
                                            int E, int NB) {
  __shared__ int cur[512];
  __shared__ int s_is64;
  int t = threadIdx.x, blk = blockIdx.x;
  for (int i = t; i < NB; i += 256) cur[i] = blk_off[(size_t)blk * NB + i];
  if (t < 64) { int r = detect64(eidx); if (t == 0) s_is64 = r; }
  __syncthreads();
  int is64 = s_is64;
  int lo = blk * CH, hi = min(lo + CH, E);
  for (int i = lo + t; i < hi; i += 256) {
    int s = eidx_at(eidx, i, is64);
    int d = eidx_at(eidx, (long long)E + i, is64);
    int pos = atomicAdd(&cur[d >> BSHIFT], 1);  // LDS atomic
    packed[pos] = ((unsigned)(d & (BSIZE - 1)) << 17) | (unsigned)s;
  }
}

// S4: one block per bucket, one node per thread. LDS hist -> rowptr/dinv
// (coalesced), then scatter csr_src within the bucket's window.
__global__ __launch_bounds__(256) void k_s4(const unsigned int* __restrict__ packed,
                                            const int* __restrict__ bucket_base,
                                            int* __restrict__ rowptr,
                                            float* __restrict__ dinv,
                                            int* __restrict__ csr_src, int n) {
  int b = blockIdx.x, t = threadIdx.x;
  int lo = bucket_base[b], hi = bucket_base[b + 1];
  __shared__ int h[256];
  __shared__ int ps[256];
  __shared__ int cur[256];
  h[t] = 0;
  __syncthreads();
  for (int i = lo + t; i < hi; i += 256)
    atomicAdd(&h[packed[i] >> 17], 1);
  __syncthreads();
  int a0 = h[t];
  ps[t] = a0;
  __syncthreads();
  for (int off = 1; off < 256; off <<= 1) {
    int x = (t >= off) ? ps[t - off] : 0;
    __syncthreads();
    ps[t] += x;
    __syncthreads();
  }
  int e0 = lo + ps[t] - a0;   // exclusive
  cur[t] = e0;
  int node = b * BSIZE + t;
  if (node < n) { rowptr[node] = e0; dinv[node] = rsqrtf((float)(a0 + 1)); }
  __syncthreads();
  for (int i = lo + t; i < hi; i += 256) {
    unsigned p = packed[i];
    int pos = atomicAdd(&cur[p >> 17], 1);  // LDS atomic
    csr_src[pos] = (int)(p & 0x1FFFFu);
  }
}

// MFMA matmul, fp32 input (layer 1): T' = bf16(dinv * (X @ W)).
// Compensated split X=Xh+Xl, W=Wh+Wl; acc = XhWh + XhWl + XlWh.
// Layouts (m89/m97): A/B lane l holds 8 contiguous k at k=(l>>4)*8+i,
// row/col = l&15; D: col=l&15, row=(l>>4)*4+reg.
template <int COUT>
__global__ __launch_bounds__(256) void k_mm_f(const float* __restrict__ X,
                                              const float* __restrict__ W,
                                              const float* __restrict__ dinv,
                                              unsigned short* __restrict__ T, int n) {
  const int NT = COUT / 16;
  int lane = threadIdx.x & 63;
  int wid = blockIdx.x * (blockDim.x >> 6) + (threadIdx.x >> 6);
  int rowb = wid * 16;
  if (rowb >= n) return;
  int lr = lane & 15;
  int lk = lane >> 4;

  bf16x8 wh[2 * NT], wl[2 * NT];
#pragma unroll
  for (int kk = 0; kk < 2; ++kk) {
#pragma unroll
    for (int nt = 0; nt < NT; ++nt) {
#pragma unroll
      for (int i = 0; i < 8; ++i) {
        int k = kk * 32 + lk * 8 + i;
        float w = W[k * COUT + nt * 16 + lr];
        unsigned short h = f2bf(w);
        wh[kk * NT + nt][i] = (short)h;
        wl[kk * NT + nt][i] = (short)f2bf(w - bf2f(h));
      }
    }
  }

  const float* ar = X + (size_t)(rowb + lr) * 64;
  bf16x8 ah[2], al[2];
#pragma unroll
  for (int kk = 0; kk < 2; ++kk) {
    float4 v0 = *(const float4*)(ar + kk * 32 + lk * 8);
    float4 v1 = *(const float4*)(ar + kk * 32 + lk * 8 + 4);
    float vv[8] = {v0.x, v0.y, v0.z, v0.w, v1.x, v1.y, v1.z, v1.w};
#pragma unroll
    for (int i = 0; i < 8; ++i) {
      unsigned short h = f2bf(vv[i]);
      ah[kk][i] = (short)h;
      al[kk][i] = (short)f2bf(vv[i] - bf2f(h));
    }
  }

  f32x4 acc[NT];
#pragma unroll
  for (int nt = 0; nt < NT; ++nt) {
    f32x4 a = {0.f, 0.f, 0.f, 0.f};
#pragma unroll
    for (int kk = 0; kk < 2; ++kk) {
      a = __builtin_amdgcn_mfma_f32_16x16x32_bf16(ah[kk], wh[kk * NT + nt], a, 0, 0, 0);
      a = __builtin_amdgcn_mfma_f32_16x16x32_bf16(ah[kk], wl[kk * NT + nt], a, 0, 0, 0);
      a = __builtin_amdgcn_mfma_f32_16x16x32_bf16(al[kk], wh[kk * NT + nt], a, 0, 0, 0);
    }
    acc[nt] = a;
  }

#pragma unroll
  for (int j = 0; j < 4; ++j) {
    int row = rowb + lk * 4 + j;
    float dr = dinv[row];
#pragma unroll
    for (int nt = 0; nt < NT; ++nt)
      T[(size_t)row * COUT + nt * 16 + lr] = f2bf(acc[nt][j] * dr);
  }
}

// MFMA matmul, bf16 input (layers 2/3): input exact -> 2-term split
// acc = A*Wh + A*Wl. A fragments loaded directly (bf16x8, 16B).
template <int COUT>
__global__ __launch_bounds__(256) void k_mm_b(const unsigned short* __restrict__ Xb,
                                              const float* __restrict__ W,
                                              const float* __restrict__ dinv,
                                              unsigned short* __restrict__ T, int n) {
  const int NT = COUT / 16;
  int lane = threadIdx.x & 63;
  int wid = blockIdx.x * (blockDim.x >> 6) + (threadIdx.x >> 6);
  int rowb = wid * 16;
  if (rowb >= n) return;
  int lr = lane & 15;
  int lk = lane >> 4;

  bf16x8 wh[2 * NT], wl[2 * NT];
#pragma unroll
  for (int kk = 0; kk < 2; ++kk) {
#pragma unroll
    for (int nt = 0; nt < NT; ++nt) {
#pragma unroll
      for (int i = 0; i < 8; ++i) {
        int k = kk * 32 + lk * 8 + i;
        float w = W[k * COUT + nt * 16 + lr];
        unsigned short h = f2bf(w);
        wh[kk * NT + nt][i] = (short)h;
        wl[kk * NT + nt][i] = (short)f2bf(w - bf2f(h));
      }
    }
  }

  const unsigned short* ar = Xb + (size_t)(rowb + lr) * 64;
  bf16x8 av[2];
#pragma unroll
  for (int kk = 0; kk < 2; ++kk)
    av[kk] = *(const bf16x8*)(ar + kk * 32 + lk * 8);

  f32x4 acc[NT];
#pragma unroll
  for (int nt = 0; nt < NT; ++nt) {
    f32x4 a = {0.f, 0.f, 0.f, 0.f};
#pragma unroll
    for (int kk = 0; kk < 2; ++kk) {
      a = __builtin_amdgcn_mfma_f32_16x16x32_bf16(av[kk], wh[kk * NT + nt], a, 0, 0, 0);
      a = __builtin_amdgcn_mfma_f32_16x16x32_bf16(av[kk], wl[kk * NT + nt], a, 0, 0, 0);
    }
    acc[nt] = a;
  }

#pragma unroll
  for (int j = 0; j < 4; ++j) {
    int row = rowb + lk * 4 + j;
    float dr = dinv[row];
#pragma unroll
    for (int nt = 0; nt < NT; ++nt)
      T[(size_t)row * COUT + nt * 16 + lr] = f2bf(acc[nt][j] * dr);
  }
}

// One wave per dst row: acc = sum T'[src[j]] (batched 8/4/1, independent
// bf16 loads, fp32 accumulate), then v = dinv*(acc + T'[row]) + b.
// OUTBF: store bf16 (intermediate activations) vs fp32 (final output).
template <int COUT, bool RELU, bool OUTBF>
__global__ __launch_bounds__(256) void k_gather(const unsigned short* __restrict__ T,
                                                const int* __restrict__ rowptr,
                                                const int* __restrict__ csr_src,
                                                const float* __restrict__ dinv,
                                                const float* __restrict__ b,
                                                void* __restrict__ outp, int n) {
  int wave = blockIdx.x * (blockDim.x >> 6) + (threadIdx.x >> 6);
  int lane = threadIdx.x & 63;
  int row = __builtin_amdgcn_readfirstlane(wave);
  if (row >= n) return;
  int beg = rowptr[row];
  int end = rowptr[row + 1];
  float dr = dinv[row];
  float a0 = 0.f, a1 = 0.f, a2 = 0.f, a3 = 0.f;
  int j = beg;
  if (lane < COUT) {
    for (; j + 8 <= end; j += 8) {
      int s0 = csr_src[j + 0], s1 = csr_src[j + 1], s2 = csr_src[j + 2], s3 = csr_src[j + 3];
      int s4 = csr_src[j + 4], s5 = csr_src[j + 5], s6 = csr_src[j + 6], s7 = csr_src[j + 7];
      float t0 = bf2f(T[(size_t)s0 * COUT + lane]);
      float t1 = bf2f(T[(size_t)s1 * COUT + lane]);
      float t2 = bf2f(T[(size_t)s2 * COUT + lane]);
      float t3 = bf2f(T[(size_t)s3 * COUT + lane]);
      float t4 = bf2f(T[(size_t)s4 * COUT + lane]);
      float t5 = bf2f(T[(size_t)s5 * COUT + lane]);
      float t6 = bf2f(T[(size_t)s6 * COUT + lane]);
      float t7 = bf2f(T[(size_t)s7 * COUT + lane]);
      a0 += t0; a1 += t1; a2 += t2; a3 += t3;
      a0 += t4; a1 += t5; a2 += t6; a3 += t7;
    }
    if (j + 4 <= end) {
      int s0 = csr_src[j + 0], s1 = csr_src[j + 1], s2 = csr_src[j + 2], s3 = csr_src[j + 3];
      float t0 = bf2f(T[(size_t)s0 * COUT + lane]);
      float t1 = bf2f(T[(size_t)s1 * COUT + lane]);
      float t2 = bf2f(T[(size_t)s2 * COUT + lane]);
      float t3 = bf2f(T[(size_t)s3 * COUT + lane]);
      a0 += t0; a1 += t1; a2 += t2; a3 += t3;
      j += 4;
    }
    for (; j < end; ++j) {
      int s = csr_src[j];
      a0 += bf2f(T[(size_t)s * COUT + lane]);
    }
    float acc = (a0 + a1) + (a2 + a3);
    float v = fmaf(dr, acc + bf2f(T[(size_t)row * COUT + lane]), b[lane]);
    if (RELU) v = fmaxf(v, 0.f);
    if (OUTBF)
      ((unsigned short*)outp)[(size_t)row * COUT + lane] = f2bf(v);
    else
      ((float*)outp)[(size_t)row * COUT + lane] = v;
  }
}

extern "C" void kernel_launch(void* const* d_in, const int* in_sizes, int n_in,
                              void* d_out, int out_size, void* d_ws, size_t ws_size,
                              hipStream_t stream) {
  const float* x  = (const float*)d_in[0];
  const void*  ei = d_in[1];
  const float* W1 = (const float*)d_in[2];
  const float* b1 = (const float*)d_in[3];
  const float* W2 = (const float*)d_in[4];
  const float* b2 = (const float*)d_in[5];
  const float* W3 = (const float*)d_in[6];
  const float* b3 = (const float*)d_in[7];
  float* out = (float*)d_out;

  const int n = in_sizes[0] / 64;   // 100000 (multiple of 16)
  const int E = in_sizes[1] / 2;    // 1000000

  const int NB   = (n + BSIZE - 1) / BSIZE;  // 391 buckets
  const int NBLK = (E + CH - 1) / CH;        // 245 edge blocks (<= 256)

  char* ws = (char*)d_ws;
  size_t off = 0;
  auto carve = [&](size_t bytes) -> void* {
    void* p = ws + off;
    off = (off + bytes + 255) & ~(size_t)255;
    return p;
  };
  float*          dinv        = (float*)carve(sizeof(float) * n);
  int*            rowptr      = (int*)carve(sizeof(int) * (n + 1));
  int*            bucket_tot  = (int*)carve(sizeof(int) * 512);
  int*            bucket_base = (int*)carve(sizeof(int) * 512);
  int*            blk_off     = (int*)carve(sizeof(int) * (size_t)NBLK * NB);
  unsigned*       packed      = (unsigned*)carve(sizeof(unsigned) * E);
  int*            csr_src     = (int*)carve(sizeof(int) * E);
  unsigned short* T           = (unsigned short*)carve(sizeof(unsigned short) * (size_t)n * 64);
  unsigned short* A           = (unsigned short*)carve(sizeof(unsigned short) * (size_t)n * 64);

  const int B = 256;
  const int gW  = (n + 3) / 4;                    // gather: 4 waves/block
  const int gMM = ((n + 15) / 16 + 3) / 4;        // mfma: 4 waves/block, 16 rows/wave

  // ---- CSR build (bucket counting sort; LDS-only fine-grained atomics) ----
  k_s1<<<NBLK, B, 0, stream>>>(ei, blk_off, E, NB);
  k_colsum<<<NB, B, 0, stream>>>(blk_off, NBLK, NB, bucket_tot);
  k_scan<<<1, 512, 0, stream>>>(bucket_tot, bucket_base, rowptr, NB, n, E);
  k_s2b<<<NB, B, 0, stream>>>(blk_off, bucket_base, NBLK, NB);
  k_s3<<<NBLK, B, 0, stream>>>(ei, blk_off, packed, E, NB);
  k_s4<<<NB, B, 0, stream>>>(packed, bucket_base, rowptr, dinv, csr_src, n);

  // ---- layer 1: x (fp32) -> A (bf16) ----
  k_mm_f<64><<<gMM, B, 0, stream>>>(x, W1, dinv, T, n);
  k_gather<64, true, true><<<gW, B, 0, stream>>>(T, rowptr, csr_src, dinv, b1, A, n);

  // ---- layer 2: A (bf16) -> A (bf16) ----
  k_mm_b<64><<<gMM, B, 0, stream>>>(A, W2, dinv, T, n);
  k_gather<64, true, true><<<gW, B, 0, stream>>>(T, rowptr, csr_src, dinv, b2, A, n);

  // ---- layer 3: A (bf16) -> out (fp32) ----
  k_mm_b<32><<<gMM, B, 0, stream>>>(A, W3, dinv, T, n);
  k_gather<32, false, false><<<gW, B, 0, stream>>>(T, rowptr, csr_src, dinv, b3, out, n);
}